// Round 11
// baseline (524.127 us; speedup 1.0000x reference)
//
#include <hip/hip_runtime.h>

// GCN: N=100000 nodes, E=1600000 edges, F_IN=F_HID=64, F_OUT=16, fp32.
//
// Reformulation (R11): defer the PairNorm column-mean through the conv:
//   pairnorm(x)@W = (x@W)*rinv - cm,  cm = colmean(x)@W
//   gather(z'-cm) + (z'self-cm) + b = Sum z' + z'self + b - (deg+1)*cm
// so matnorm stores z' = (x@W)*rinv (no global dependency), and each gather
// applies the rank-1 cm correction inline. The gather holds the full relu'd
// row o in registers -> fuse the NEXT layer's matvec into its epilogue:
//   gather_l1: ... -> o -> rownorm -> o@W2*rinv -> z2' bf16 (+ cs2 colsum)
//   gather_l2: ... -> o -> o@W3 -> z3 bf16
// Deletes colsum/matnorm2/mat16 (3 dispatches, ~80 MB traffic). Edges packed
// (src<<11)|(dst&2047) halve scatter/fillsort traffic. 9 dispatches total.

#define NHB 64      // hi-buckets of 2048 nodes; hi = dst >> 11

__device__ __forceinline__ unsigned short f2bf(float f) {
  unsigned u = __builtin_bit_cast(unsigned, f);
  u += 0x7FFFu + ((u >> 16) & 1u);    // round-to-nearest-even
  return (unsigned short)(u >> 16);
}
__device__ __forceinline__ float bf2f(unsigned short h) {
  return __builtin_bit_cast(float, ((unsigned)h) << 16);
}

// ------- prelude: cntA histogram of dst (hi-buckets) + column sums of feat -------
__global__ __launch_bounds__(256) void prelude_kernel(
    const int* __restrict__ dst, int* __restrict__ cntA, int E,
    const float* __restrict__ x, float* __restrict__ cs, int n4) {
  __shared__ int lc[NHB];
  __shared__ float lds[16][64];
  const int t = threadIdx.x;
  if (t < NHB) lc[t] = 0;
  __syncthreads();
  const int stride = gridDim.x * blockDim.x;
  for (int e = blockIdx.x * blockDim.x + t; e < E; e += stride)
    atomicAdd(&lc[__builtin_nontemporal_load(&dst[e]) >> 11], 1);

  float s0 = 0.f, s1 = 0.f, s2 = 0.f, s3 = 0.f;
  for (int i = blockIdx.x * blockDim.x + t; i < n4; i += stride) {
    float4 v = ((const float4*)x)[i];
    s0 += v.x; s1 += v.y; s2 += v.z; s3 += v.w;
  }
  const int r = t >> 4;
  const int cq = (t & 15) * 4;
  lds[r][cq + 0] = s0; lds[r][cq + 1] = s1; lds[r][cq + 2] = s2; lds[r][cq + 3] = s3;
  __syncthreads();
  if (t < NHB && lc[t]) atomicAdd(&cntA[t], lc[t]);
  if (t < 64) {
    float tot = 0.f;
    #pragma unroll
    for (int rr = 0; rr < 16; ++rr) tot += lds[rr][t];
    unsafeAtomicAdd(&cs[t], tot);
  }
}

// ------- scanA: bucket scan + cmW1[t] = invN * sum_k cs1[k]*W1[k][t] -------
__global__ void scanA_kernel(const int* __restrict__ cntA,
                             int* __restrict__ baseA, int* __restrict__ curA,
                             const float* __restrict__ cs1,
                             const float* __restrict__ W1,
                             float* __restrict__ cmW1, int NHI, float invN) {
  const int t = threadIdx.x;   // 64 threads
  if (t == 0) {
    int acc = 0;
    for (int p = 0; p < NHI; ++p) { baseA[p] = acc; curA[p] = acc; acc += cntA[p]; }
    baseA[NHI] = acc;
  }
  float cm = 0.f;
  #pragma unroll
  for (int k = 0; k < 64; ++k) cm = fmaf(cs1[k], W1[k * 64 + t], cm);
  cmW1[t] = cm * invN;
}

// ------------- matnorm1: z1' = (feat @ W1) * rinv, bf16 (cm deferred) -------------
__global__ __launch_bounds__(256) void matnorm_kernel(
    const float* __restrict__ x, const float* __restrict__ W,
    unsigned short* __restrict__ z, int N) {
  const int lane = threadIdx.x & 63;
  const int wid  = blockIdx.x * (blockDim.x >> 6) + (threadIdx.x >> 6);
  const int nw   = gridDim.x * (blockDim.x >> 6);

  float w[64];
  #pragma unroll
  for (int k = 0; k < 64; ++k) w[k] = W[k * 64 + lane];

  for (int row = wid; row < N; row += nw) {
    const float xv = x[(size_t)row * 64 + lane];
    float ss = xv * xv;
    #pragma unroll
    for (int m = 1; m < 64; m <<= 1) ss += __shfl_xor(ss, m, 64);
    const float rinv = 1.0f / sqrtf(1e-6f + ss);
    float acc = 0.f;
    #pragma unroll
    for (int k = 0; k < 64; ++k) {
      const float xk = __builtin_bit_cast(
          float, __builtin_amdgcn_readlane(__builtin_bit_cast(int, xv), k));
      acc = fmaf(xk, w[k], acc);
    }
    z[(size_t)row * 64 + lane] = f2bf(acc * rinv);
  }
}

// ================= CSR build: hi-bucket radix + LDS counting sort =================
// Edge packed as (src << 11) | (dst & 2047): src < 2^17 -> 28 bits used.

#define TILE 2048
#define CAPA 96   // per-tile per-bucket mean 42, sigma 6.4 -> 8.5 sigma + spill
__global__ __launch_bounds__(256) void scatterA_kernel(
    const int* __restrict__ src, const int* __restrict__ dst,
    int* __restrict__ curA, unsigned* __restrict__ ppack, int E) {
  __shared__ unsigned lpk[NHB][CAPA];
  __shared__ int lcnt[NHB], lbase[NHB];
  const int t = threadIdx.x;
  if (t < NHB) lcnt[t] = 0;
  __syncthreads();
  const int ntiles = (E + TILE - 1) / TILE;
  for (int tile = blockIdx.x; tile < ntiles; tile += gridDim.x) {
    const int base = tile * TILE;
    #pragma unroll
    for (int j = 0; j < TILE / 256; ++j) {
      const int e = base + j * 256 + t;   // coalesced
      if (e < E) {
        const int d = __builtin_nontemporal_load(&dst[e]);
        const int s = __builtin_nontemporal_load(&src[e]);
        const unsigned pw = ((unsigned)s << 11) | ((unsigned)d & 2047u);
        const int p = d >> 11;
        const int slot = atomicAdd(&lcnt[p], 1);
        if (slot < CAPA) lpk[p][slot] = pw;
        else ppack[atomicAdd(&curA[p], 1)] = pw;  // rare spill
      }
    }
    __syncthreads();
    if (t < NHB) {
      int c = lcnt[t]; if (c > CAPA) c = CAPA;
      lbase[t] = c ? atomicAdd(&curA[t], c) : 0;
      lcnt[t] = c;
    }
    __syncthreads();
    for (int p = 0; p < NHB; ++p) {
      const int c = lcnt[p];
      if (t < c) ppack[lbase[p] + t] = lpk[p][t];  // contiguous chunk
    }
    __syncthreads();
    if (t < NHB) lcnt[t] = 0;
    __syncthreads();
  }
}

// One workgroup (1024 thr) per hi-bucket: LDS counting sort by exact dst.
__global__ __launch_bounds__(1024) void fillsort_kernel(
    const unsigned* __restrict__ ppack, const int* __restrict__ baseA,
    int* __restrict__ rowstart, int* __restrict__ csr, int N, int E) {
  __shared__ int hist[2048];
  __shared__ int bs[1024];
  const int t = threadIdx.x;
  const int h = blockIdx.x;
  const int nlo = h << 11;
  const int elo = baseA[h], ehi = baseA[h + 1];

  for (int i = t; i < 2048; i += 1024) hist[i] = 0;
  __syncthreads();

  // phase 1: histogram (4 independent loads in flight)
  int e = elo + t;
  for (; e + 3 * 1024 < ehi; e += 4 * 1024) {
    const unsigned p0 = ppack[e], p1 = ppack[e + 1024],
                   p2 = ppack[e + 2048], p3 = ppack[e + 3072];
    atomicAdd(&hist[p0 & 2047u], 1); atomicAdd(&hist[p1 & 2047u], 1);
    atomicAdd(&hist[p2 & 2047u], 1); atomicAdd(&hist[p3 & 2047u], 1);
  }
  for (; e < ehi; e += 1024) atomicAdd(&hist[ppack[e] & 2047u], 1);
  __syncthreads();

  // exclusive scan of hist[2048]
  const int c0 = hist[2 * t], c1 = hist[2 * t + 1];
  const int s = c0 + c1;
  bs[t] = s;
  __syncthreads();
  for (int off = 1; off < 1024; off <<= 1) {
    const int v = (t >= off) ? bs[t - off] : 0;
    __syncthreads();
    bs[t] += v;
    __syncthreads();
  }
  const int excl = bs[t] - s;

  const int n0 = nlo + 2 * t;
  hist[2 * t] = excl;
  hist[2 * t + 1] = excl + c0;
  if (n0 < N)     rowstart[n0]     = elo + excl;
  if (n0 + 1 < N) rowstart[n0 + 1] = elo + excl + c0;
  if (h == 0 && t == 0) rowstart[N] = E;
  __syncthreads();

  // phase 2: place (bucket's csr window ~131 KB, single CU owner)
  e = elo + t;
  for (; e + 3 * 1024 < ehi; e += 4 * 1024) {
    const unsigned p0 = ppack[e],        p1 = ppack[e + 1024];
    const unsigned p2 = ppack[e + 2048], p3 = ppack[e + 3072];
    csr[elo + atomicAdd(&hist[p0 & 2047u], 1)] = (int)(p0 >> 11);
    csr[elo + atomicAdd(&hist[p1 & 2047u], 1)] = (int)(p1 >> 11);
    csr[elo + atomicAdd(&hist[p2 & 2047u], 1)] = (int)(p2 >> 11);
    csr[elo + atomicAdd(&hist[p3 & 2047u], 1)] = (int)(p3 >> 11);
  }
  for (; e < ehi; e += 1024) {
    const unsigned p = ppack[e];
    csr[elo + atomicAdd(&hist[p & 2047u], 1)] = (int)(p >> 11);
  }
}

// ------- gather_l1: o = relu(Sum z1' + self + b1 - (deg+1)*cmW1);
//         z2' = (o @ W2) * rinv2 (bf16); cs2 += colsum(o). 16 waves/block. -------
__global__ __launch_bounds__(1024) void gather_l1_kernel(
    const unsigned short* __restrict__ z1, const float* __restrict__ W2,
    const float* __restrict__ b1, const float* __restrict__ cmW1,
    const int* __restrict__ rowstart, const int* __restrict__ csr,
    unsigned short* __restrict__ z2, float* __restrict__ cs2, int N) {
  const int lane = threadIdx.x & 63;
  const int w = threadIdx.x >> 6;
  const int node = blockIdx.x * 16 + w;
  float o = 0.f;
  if (node < N) {
    const int nd = __builtin_amdgcn_readfirstlane(node);
    const int start = rowstart[nd];
    const int end   = rowstart[nd + 1];
    const unsigned short hs = z1[(size_t)nd * 64 + lane];
    float a0 = 0.f, a1 = 0.f, a2 = 0.f, a3 = 0.f;
    int e = start;
    for (; e + 16 <= end; e += 16) {   // R8's proven 16-deep ladder
      unsigned short h[16];
      #pragma unroll
      for (int j = 0; j < 16; ++j) h[j] = z1[(size_t)csr[e + j] * 64 + lane];
      #pragma unroll
      for (int j = 0; j < 16; j += 4) {
        a0 += bf2f(h[j + 0]); a1 += bf2f(h[j + 1]);
        a2 += bf2f(h[j + 2]); a3 += bf2f(h[j + 3]);
      }
    }
    for (; e + 4 <= end; e += 4) {
      unsigned short h[4];
      #pragma unroll
      for (int j = 0; j < 4; ++j) h[j] = z1[(size_t)csr[e + j] * 64 + lane];
      a0 += bf2f(h[0]); a1 += bf2f(h[1]); a2 += bf2f(h[2]); a3 += bf2f(h[3]);
    }
    for (; e < end; ++e) a0 += bf2f(z1[(size_t)csr[e] * 64 + lane]);
    const float sum = (a0 + a1) + (a2 + a3);
    const float degp1 = (float)(end - start + 1);
    o = fmaxf(bf2f(hs) + b1[lane] + sum - degp1 * cmW1[lane], 0.f);
    // pairnorm rownorm of o
    float ss = o * o;
    #pragma unroll
    for (int m = 1; m < 64; m <<= 1) ss += __shfl_xor(ss, m, 64);
    const float rinv = 1.0f / sqrtf(1e-6f + ss);
    // matvec: z2'[lane] = rinv * sum_k o[k] * W2[k][lane]
    float acc = 0.f;
    #pragma unroll
    for (int k = 0; k < 64; ++k) {
      const float ok = __builtin_bit_cast(
          float, __builtin_amdgcn_readlane(__builtin_bit_cast(int, o), k));
      acc = fmaf(ok, W2[k * 64 + lane], acc);
    }
    z2[(size_t)nd * 64 + lane] = f2bf(acc * rinv);
  }
  // block-level colsum of o (16 waves -> 64 atomics/block; 6250 blocks)
  __shared__ float lcs[16][64];
  lcs[w][lane] = o;
  __syncthreads();
  if (threadIdx.x < 64) {
    float tot = 0.f;
    #pragma unroll
    for (int r = 0; r < 16; ++r) tot += lcs[r][threadIdx.x];
    unsafeAtomicAdd(&cs2[threadIdx.x], tot);
  }
}

// ------- gather_l2: o = relu(Sum z2' + self + b2 - (deg+1)*cm2);
//         z3 = o @ W3 (bf16, 64->16). cm2 computed per-wave from cs2. -------
__global__ __launch_bounds__(256) void gather_l2_kernel(
    const unsigned short* __restrict__ z2, const float* __restrict__ W2,
    const float* __restrict__ cs2, const float* __restrict__ b2,
    const float* __restrict__ W3, const int* __restrict__ rowstart,
    const int* __restrict__ csr, unsigned short* __restrict__ z3,
    int N, float invN) {
  const int lane = threadIdx.x & 63;
  int node = blockIdx.x * (blockDim.x >> 6) + (threadIdx.x >> 6);
  if (node >= N) return;
  node = __builtin_amdgcn_readfirstlane(node);
  float cm = 0.f;
  #pragma unroll
  for (int k = 0; k < 64; ++k) cm = fmaf(cs2[k], W2[k * 64 + lane], cm);
  cm *= invN;
  const int start = rowstart[node];
  const int end   = rowstart[node + 1];
  const unsigned short hs = z2[(size_t)node * 64 + lane];
  float a0 = 0.f, a1 = 0.f, a2 = 0.f, a3 = 0.f;
  int e = start;
  for (; e + 16 <= end; e += 16) {
    unsigned short h[16];
    #pragma unroll
    for (int j = 0; j < 16; ++j) h[j] = z2[(size_t)csr[e + j] * 64 + lane];
    #pragma unroll
    for (int j = 0; j < 16; j += 4) {
      a0 += bf2f(h[j + 0]); a1 += bf2f(h[j + 1]);
      a2 += bf2f(h[j + 2]); a3 += bf2f(h[j + 3]);
    }
  }
  for (; e + 4 <= end; e += 4) {
    unsigned short h[4];
    #pragma unroll
    for (int j = 0; j < 4; ++j) h[j] = z2[(size_t)csr[e + j] * 64 + lane];
    a0 += bf2f(h[0]); a1 += bf2f(h[1]); a2 += bf2f(h[2]); a3 += bf2f(h[3]);
  }
  for (; e < end; ++e) a0 += bf2f(z2[(size_t)csr[e] * 64 + lane]);
  const float sum = (a0 + a1) + (a2 + a3);
  const float degp1 = (float)(end - start + 1);
  const float o = fmaxf(bf2f(hs) + b2[lane] + sum - degp1 * cm, 0.f);
  // matvec 64->16: z3[j] = sum_k o[k] * W3[k][j] (no pairnorm on layer 3)
  const int j = lane & 15;
  float acc = 0.f;
  #pragma unroll
  for (int k = 0; k < 64; ++k) {
    const float ok = __builtin_bit_cast(
        float, __builtin_amdgcn_readlane(__builtin_bit_cast(int, o), k));
    acc = fmaf(ok, W3[k * 16 + j], acc);
  }
  if (lane < 16) z3[(size_t)node * 16 + lane] = f2bf(acc);
}

// ------- gather16: out[d] = z3[d] + b3 + sum z3[src]; 16 feat x 4 edge-groups -------
__global__ __launch_bounds__(256) void gather16_kernel(
    const unsigned short* __restrict__ z3, const float* __restrict__ b3,
    const int* __restrict__ rowstart, const int* __restrict__ csr,
    float* __restrict__ out, int N) {
  const int lane = threadIdx.x & 63;
  const int f = lane & 15;
  const int g = lane >> 4;
  int node = blockIdx.x * (blockDim.x >> 6) + (threadIdx.x >> 6);
  if (node >= N) return;
  node = __builtin_amdgcn_readfirstlane(node);
  const int start = rowstart[node];
  const int end   = rowstart[node + 1];
  float acc0 = 0.f, acc1 = 0.f;
  int e = start + g;
  for (; e + 4 < end; e += 8) {
    acc0 += bf2f(z3[(size_t)csr[e] * 16 + f]);
    acc1 += bf2f(z3[(size_t)csr[e + 4] * 16 + f]);
  }
  if (e < end) acc0 += bf2f(z3[(size_t)csr[e] * 16 + f]);
  float acc = acc0 + acc1;
  acc += __shfl_xor(acc, 16, 64);
  acc += __shfl_xor(acc, 32, 64);
  if (lane < 16)
    out[(size_t)node * 16 + f] = bf2f(z3[(size_t)node * 16 + f]) + b3[f] + acc;
}

extern "C" void kernel_launch(void* const* d_in, const int* in_sizes, int n_in,
                              void* d_out, int out_size, void* d_ws, size_t ws_size,
                              hipStream_t stream) {
  const float* feat = (const float*)d_in[0];
  const float* W1 = (const float*)d_in[1];
  const float* b1 = (const float*)d_in[2];
  const float* W2 = (const float*)d_in[3];
  const float* b2 = (const float*)d_in[4];
  const float* W3 = (const float*)d_in[5];
  const float* b3 = (const float*)d_in[6];
  const int* src = (const int*)d_in[7];
  const int* dst = (const int*)d_in[8];
  const int N = in_sizes[0] / 64;
  const int E = in_sizes[7];
  float* out = (float*)d_out;

  // workspace layout
  unsigned short* z1b = (unsigned short*)d_ws;            // N*64 bf16
  unsigned short* z2b = z1b + (size_t)N * 64;             // N*64 bf16
  unsigned short* z3b = z2b + (size_t)N * 64;             // N*16 bf16
  int* cntA  = (int*)(z3b + (size_t)N * 16);              // NHB  } one memset
  float* cs1 = (float*)(cntA + NHB);                      // 64   } covers
  float* cs2 = cs1 + 64;                                  // 64   } these 3
  float* cmW1   = cs2 + 64;                               // 64 (scanA writes)
  int* baseA    = (int*)(cmW1 + 64);                      // NHB+1
  int* curA     = baseA + NHB + 1;                        // NHB
  int* rowstart = curA + NHB;                             // N+1
  int* csr      = rowstart + N + 1;                       // E
  // ppack aliases z2b (dead until gather_l1 writes it, after fillsort)
  unsigned* ppack = (unsigned*)z2b;                       // E uints <= N*64*2 B

  const int NHI = (N + 2047) >> 11;       // 49
  const int node_blocks = (N + 3) / 4;    // 4 waves/block kernels
  const int l1_blocks   = (N + 15) / 16;  // 16 waves/block (gather_l1)
  const float invN = 1.0f / (float)N;

  // ---- CSR build + layer-1 colsum ----
  hipMemsetAsync(cntA, 0, (NHB + 128) * sizeof(int), stream);  // cntA+cs1+cs2
  prelude_kernel<<<512, 256, 0, stream>>>(dst, cntA, E, feat, cs1, N * 16);
  scanA_kernel<<<1, 64, 0, stream>>>(cntA, baseA, curA, cs1, W1, cmW1, NHI, invN);
  scatterA_kernel<<<512, 256, 0, stream>>>(src, dst, curA, ppack, E);
  fillsort_kernel<<<NHI, 1024, 0, stream>>>(ppack, baseA, rowstart, csr, N, E);

  // ---- layer 1 matvec (cm deferred into gather_l1) ----
  matnorm_kernel<<<1024, 256, 0, stream>>>(feat, W1, z1b, N);

  // ---- fused gathers: l1 (-> z2' + cs2), l2 (-> z3), final 16-wide ----
  gather_l1_kernel<<<l1_blocks, 1024, 0, stream>>>(z1b, W2, b1, cmW1,
                                                   rowstart, csr, z2b, cs2, N);
  gather_l2_kernel<<<node_blocks, 256, 0, stream>>>(z2b, W2, cs2, b2, W3,
                                                    rowstart, csr, z3b, N, invN);
  gather16_kernel<<<node_blocks, 256, 0, stream>>>(z3b, b3, rowstart, csr, out, N);
}

// Round 12
// 409.915 us; speedup vs baseline: 1.2786x; 1.2786x over previous
//
#include <hip/hip_runtime.h>

// GCN: N=100000 nodes, E=1600000 edges, F_IN=F_HID=64, F_OUT=16, fp32.
//
// R11 -> R12: gather_l1's fusion regressed (block barrier tail + per-node W2
// reload); gather_l2's barrier-free W3 fusion was fine. R12 = R10 base +
// only the proven pieces:
//   - mat16 fused into gather_l2 epilogue (no barrier, small W3):
//     deletes mat16 dispatch + 51 MB of B round-trip traffic.
//   - packed edges (src<<10)|(dst&1023): halves scatter/fillsort traffic.
//   - 1024-node buckets (NHI=98): 2x fillsort CU utilization, 1 ctr/thread.

#define NHB 128     // max hi-buckets of 1024 nodes (N <= 131072); hi = dst >> 10

__device__ __forceinline__ unsigned short f2bf(float f) {
  unsigned u = __builtin_bit_cast(unsigned, f);
  u += 0x7FFFu + ((u >> 16) & 1u);    // round-to-nearest-even
  return (unsigned short)(u >> 16);
}
__device__ __forceinline__ float bf2f(unsigned short h) {
  return __builtin_bit_cast(float, ((unsigned)h) << 16);
}

// ------- prelude: cntA histogram of dst (hi-buckets) + column sums of feat -------
__global__ __launch_bounds__(256) void prelude_kernel(
    const int* __restrict__ dst, int* __restrict__ cntA, int E,
    const float* __restrict__ x, float* __restrict__ cs, int n4) {
  __shared__ int lc[NHB];
  __shared__ float lds[16][64];
  const int t = threadIdx.x;
  if (t < NHB) lc[t] = 0;
  __syncthreads();
  const int stride = gridDim.x * blockDim.x;
  for (int e = blockIdx.x * blockDim.x + t; e < E; e += stride)
    atomicAdd(&lc[__builtin_nontemporal_load(&dst[e]) >> 10], 1);

  float s0 = 0.f, s1 = 0.f, s2 = 0.f, s3 = 0.f;
  for (int i = blockIdx.x * blockDim.x + t; i < n4; i += stride) {
    float4 v = ((const float4*)x)[i];
    s0 += v.x; s1 += v.y; s2 += v.z; s3 += v.w;
  }
  const int r = t >> 4;
  const int cq = (t & 15) * 4;
  lds[r][cq + 0] = s0; lds[r][cq + 1] = s1; lds[r][cq + 2] = s2; lds[r][cq + 3] = s3;
  __syncthreads();
  if (t < NHB && lc[t]) atomicAdd(&cntA[t], lc[t]);
  if (t < 64) {
    float tot = 0.f;
    #pragma unroll
    for (int rr = 0; rr < 16; ++rr) tot += lds[rr][t];
    unsafeAtomicAdd(&cs[t], tot);
  }
}

// ---------------- column sums of B (already relu'd by gather64) ----------------
__global__ void colsum_kernel(const float* __restrict__ x, float* __restrict__ cs,
                              int n4) {
  __shared__ float lds[16][64];
  float s0 = 0.f, s1 = 0.f, s2 = 0.f, s3 = 0.f;
  const int t = threadIdx.x;
  const int stride = gridDim.x * blockDim.x;
  for (int i = blockIdx.x * blockDim.x + t; i < n4; i += stride) {
    float4 v = ((const float4*)x)[i];
    s0 += v.x; s1 += v.y; s2 += v.z; s3 += v.w;
  }
  const int r = t >> 4;
  const int cq = (t & 15) * 4;
  lds[r][cq + 0] = s0; lds[r][cq + 1] = s1; lds[r][cq + 2] = s2; lds[r][cq + 3] = s3;
  __syncthreads();
  if (t < 64) {
    float tot = 0.f;
    #pragma unroll
    for (int rr = 0; rr < 16; ++rr) tot += lds[rr][t];
    unsafeAtomicAdd(&cs[t], tot);
  }
}

// ------------- fused: z = (x @ W) * rinv - cm, bf16 out; cm from cs in staging -------------
__global__ __launch_bounds__(256) void matnorm_kernel(
    const float* x, const float* __restrict__ W,
    const float* __restrict__ cs, unsigned short* __restrict__ z,
    int N, float invN) {
  const int lane = threadIdx.x & 63;
  const int wid  = blockIdx.x * (blockDim.x >> 6) + (threadIdx.x >> 6);
  const int nw   = gridDim.x * (blockDim.x >> 6);

  float w[64];
  float cm = 0.f;
  #pragma unroll
  for (int k = 0; k < 64; ++k) {
    w[k] = W[k * 64 + lane];
    cm = fmaf(cs[k], w[k], cm);    // cs[k] uniform scalar load
  }
  cm *= invN;

  for (int row = wid; row < N; row += nw) {
    const float xv = x[(size_t)row * 64 + lane];
    float ss = xv * xv;
    #pragma unroll
    for (int m = 1; m < 64; m <<= 1) ss += __shfl_xor(ss, m, 64);
    const float rinv = 1.0f / sqrtf(1e-6f + ss);
    float acc = 0.f;
    #pragma unroll
    for (int k = 0; k < 64; ++k) {
      const float xk = __builtin_bit_cast(
          float, __builtin_amdgcn_readlane(__builtin_bit_cast(int, xv), k));
      acc = fmaf(xk, w[k], acc);
    }
    z[(size_t)row * 64 + lane] = f2bf(acc * rinv - cm);
  }
}

// ================= CSR build: hi-bucket radix + LDS counting sort =================
// Edge packed as (src << 10) | (dst & 1023): src < 2^17 -> 27 bits used.

__global__ void scanA_kernel(const int* __restrict__ cntA,
                             int* __restrict__ baseA, int* __restrict__ curA,
                             int NHI) {
  if (threadIdx.x == 0) {
    int acc = 0;
    for (int p = 0; p < NHI; ++p) { baseA[p] = acc; curA[p] = acc; acc += cntA[p]; }
    baseA[NHI] = acc;
  }
}

#define TILE 2048
#define CAPA 48   // per-tile per-bucket mean 21, sigma 4.6 -> ~6 sigma + spill
__global__ __launch_bounds__(256) void scatterA_kernel(
    const int* __restrict__ src, const int* __restrict__ dst,
    int* __restrict__ curA, unsigned* __restrict__ ppack, int E) {
  __shared__ unsigned lpk[NHB][CAPA];
  __shared__ int lcnt[NHB], lbase[NHB];
  const int t = threadIdx.x;
  if (t < NHB) lcnt[t] = 0;
  __syncthreads();
  const int ntiles = (E + TILE - 1) / TILE;
  for (int tile = blockIdx.x; tile < ntiles; tile += gridDim.x) {
    const int base = tile * TILE;
    #pragma unroll
    for (int j = 0; j < TILE / 256; ++j) {
      const int e = base + j * 256 + t;   // coalesced
      if (e < E) {
        const int d = __builtin_nontemporal_load(&dst[e]);
        const int s = __builtin_nontemporal_load(&src[e]);
        const unsigned pw = ((unsigned)s << 10) | ((unsigned)d & 1023u);
        const int p = d >> 10;
        const int slot = atomicAdd(&lcnt[p], 1);
        if (slot < CAPA) lpk[p][slot] = pw;
        else ppack[atomicAdd(&curA[p], 1)] = pw;  // rare spill
      }
    }
    __syncthreads();
    if (t < NHB) {
      int c = lcnt[t]; if (c > CAPA) c = CAPA;
      lbase[t] = c ? atomicAdd(&curA[t], c) : 0;
      lcnt[t] = c;
    }
    __syncthreads();
    for (int p = 0; p < NHB; ++p) {
      const int c = lcnt[p];
      if (t < c) ppack[lbase[p] + t] = lpk[p][t];  // contiguous chunk
    }
    __syncthreads();
    if (t < NHB) lcnt[t] = 0;
    __syncthreads();
  }
}

// One workgroup (1024 thr) per 1024-node bucket: LDS counting sort by exact dst.
// 1 counter per thread; ~16K edges/bucket; csr window ~65 KB on one CU.
__global__ __launch_bounds__(1024) void fillsort_kernel(
    const unsigned* __restrict__ ppack, const int* __restrict__ baseA,
    int* __restrict__ rowstart, int* __restrict__ csr, int N, int E) {
  __shared__ int hist[1024];
  __shared__ int bs[1024];
  const int t = threadIdx.x;
  const int h = blockIdx.x;
  const int nlo = h << 10;
  const int elo = baseA[h], ehi = baseA[h + 1];

  hist[t] = 0;
  __syncthreads();

  // phase 1: histogram (4 independent loads in flight)
  int e = elo + t;
  for (; e + 3 * 1024 < ehi; e += 4 * 1024) {
    const unsigned p0 = ppack[e], p1 = ppack[e + 1024],
                   p2 = ppack[e + 2048], p3 = ppack[e + 3072];
    atomicAdd(&hist[p0 & 1023u], 1); atomicAdd(&hist[p1 & 1023u], 1);
    atomicAdd(&hist[p2 & 1023u], 1); atomicAdd(&hist[p3 & 1023u], 1);
  }
  for (; e < ehi; e += 1024) atomicAdd(&hist[ppack[e] & 1023u], 1);
  __syncthreads();

  // exclusive scan (1024-wide Hillis-Steele, 1 counter/thread)
  const int c = hist[t];
  bs[t] = c;
  __syncthreads();
  for (int off = 1; off < 1024; off <<= 1) {
    const int v = (t >= off) ? bs[t - off] : 0;
    __syncthreads();
    bs[t] += v;
    __syncthreads();
  }
  const int excl = bs[t] - c;

  hist[t] = excl;                    // LDS cursor
  const int n0 = nlo + t;
  if (n0 < N) rowstart[n0] = elo + excl;
  if (h == 0 && t == 0) rowstart[N] = E;
  __syncthreads();

  // phase 2: place
  e = elo + t;
  for (; e + 3 * 1024 < ehi; e += 4 * 1024) {
    const unsigned p0 = ppack[e],        p1 = ppack[e + 1024];
    const unsigned p2 = ppack[e + 2048], p3 = ppack[e + 3072];
    csr[elo + atomicAdd(&hist[p0 & 1023u], 1)] = (int)(p0 >> 10);
    csr[elo + atomicAdd(&hist[p1 & 1023u], 1)] = (int)(p1 >> 10);
    csr[elo + atomicAdd(&hist[p2 & 1023u], 1)] = (int)(p2 >> 10);
    csr[elo + atomicAdd(&hist[p3 & 1023u], 1)] = (int)(p3 >> 10);
  }
  for (; e < ehi; e += 1024) {
    const unsigned p = ppack[e];
    csr[elo + atomicAdd(&hist[p & 1023u], 1)] = (int)(p >> 10);
  }
}

// ------- gather64: agg[d] = relu(z[d] + b + sum_{e} z[src_e]) -------
// R8's proven form: one node/wave then exit; 16-deep ILP; uniform scalar base.
__global__ __launch_bounds__(256) void gather64_kernel(
    const unsigned short* __restrict__ z, const float* __restrict__ b,
    const int* __restrict__ rowstart, const int* __restrict__ csr,
    float* __restrict__ agg, int N) {
  const int lane = threadIdx.x & 63;
  int node = blockIdx.x * (blockDim.x >> 6) + (threadIdx.x >> 6);
  if (node >= N) return;
  node = __builtin_amdgcn_readfirstlane(node);
  const int start = rowstart[node];
  const int end   = rowstart[node + 1];
  const unsigned short hs = z[(size_t)node * 64 + lane];
  float a0 = 0.f, a1 = 0.f, a2 = 0.f, a3 = 0.f;
  int e = start;
  for (; e + 16 <= end; e += 16) {
    unsigned short h[16];
    #pragma unroll
    for (int j = 0; j < 16; ++j) h[j] = z[(size_t)csr[e + j] * 64 + lane];
    #pragma unroll
    for (int j = 0; j < 16; j += 4) {
      a0 += bf2f(h[j + 0]); a1 += bf2f(h[j + 1]);
      a2 += bf2f(h[j + 2]); a3 += bf2f(h[j + 3]);
    }
  }
  for (; e + 4 <= end; e += 4) {
    unsigned short h[4];
    #pragma unroll
    for (int j = 0; j < 4; ++j) h[j] = z[(size_t)csr[e + j] * 64 + lane];
    a0 += bf2f(h[0]); a1 += bf2f(h[1]); a2 += bf2f(h[2]); a3 += bf2f(h[3]);
  }
  for (; e < end; ++e) a0 += bf2f(z[(size_t)csr[e] * 64 + lane]);
  const float sum = (a0 + a1) + (a2 + a3);
  agg[(size_t)node * 64 + lane] = fmaxf(bf2f(hs) + b[lane] + sum, 0.f);
}

// ------- gather_l2: o = relu(z2[d] + b2 + sum z2[src]); z3 = o @ W3 (bf16) -------
// Same gather core; barrier-free fused 64->16 matvec epilogue (R11-proven).
__global__ __launch_bounds__(256) void gather_l2_kernel(
    const unsigned short* __restrict__ z2, const float* __restrict__ b2,
    const float* __restrict__ W3, const int* __restrict__ rowstart,
    const int* __restrict__ csr, unsigned short* __restrict__ z3, int N) {
  const int lane = threadIdx.x & 63;
  int node = blockIdx.x * (blockDim.x >> 6) + (threadIdx.x >> 6);
  if (node >= N) return;
  node = __builtin_amdgcn_readfirstlane(node);
  const int start = rowstart[node];
  const int end   = rowstart[node + 1];
  const unsigned short hs = z2[(size_t)node * 64 + lane];
  float a0 = 0.f, a1 = 0.f, a2 = 0.f, a3 = 0.f;
  int e = start;
  for (; e + 16 <= end; e += 16) {
    unsigned short h[16];
    #pragma unroll
    for (int j = 0; j < 16; ++j) h[j] = z2[(size_t)csr[e + j] * 64 + lane];
    #pragma unroll
    for (int j = 0; j < 16; j += 4) {
      a0 += bf2f(h[j + 0]); a1 += bf2f(h[j + 1]);
      a2 += bf2f(h[j + 2]); a3 += bf2f(h[j + 3]);
    }
  }
  for (; e + 4 <= end; e += 4) {
    unsigned short h[4];
    #pragma unroll
    for (int j = 0; j < 4; ++j) h[j] = z2[(size_t)csr[e + j] * 64 + lane];
    a0 += bf2f(h[0]); a1 += bf2f(h[1]); a2 += bf2f(h[2]); a3 += bf2f(h[3]);
  }
  for (; e < end; ++e) a0 += bf2f(z2[(size_t)csr[e] * 64 + lane]);
  const float sum = (a0 + a1) + (a2 + a3);
  const float o = fmaxf(bf2f(hs) + b2[lane] + sum, 0.f);
  // fused 64->16 matvec: z3[j] = sum_k o[k] * W3[k][j]
  const int j = lane & 15;
  float acc = 0.f;
  #pragma unroll
  for (int k = 0; k < 64; ++k) {
    const float ok = __builtin_bit_cast(
        float, __builtin_amdgcn_readlane(__builtin_bit_cast(int, o), k));
    acc = fmaf(ok, W3[k * 16 + j], acc);
  }
  if (lane < 16) z3[(size_t)node * 16 + lane] = f2bf(acc);
}

// ------- gather16: out[d] = z3[d] + b3 + sum z3[src]; 16 feat x 4 edge-groups -------
__global__ __launch_bounds__(256) void gather16_kernel(
    const unsigned short* __restrict__ z3, const float* __restrict__ b3,
    const int* __restrict__ rowstart, const int* __restrict__ csr,
    float* __restrict__ out, int N) {
  const int lane = threadIdx.x & 63;
  const int f = lane & 15;
  const int g = lane >> 4;
  int node = blockIdx.x * (blockDim.x >> 6) + (threadIdx.x >> 6);
  if (node >= N) return;
  node = __builtin_amdgcn_readfirstlane(node);
  const int start = rowstart[node];
  const int end   = rowstart[node + 1];
  float acc0 = 0.f, acc1 = 0.f;
  int e = start + g;
  for (; e + 4 < end; e += 8) {
    acc0 += bf2f(z3[(size_t)csr[e] * 16 + f]);
    acc1 += bf2f(z3[(size_t)csr[e + 4] * 16 + f]);
  }
  if (e < end) acc0 += bf2f(z3[(size_t)csr[e] * 16 + f]);
  float acc = acc0 + acc1;
  acc += __shfl_xor(acc, 16, 64);
  acc += __shfl_xor(acc, 32, 64);
  if (lane < 16)
    out[(size_t)node * 16 + f] = bf2f(z3[(size_t)node * 16 + f]) + b3[f] + acc;
}

extern "C" void kernel_launch(void* const* d_in, const int* in_sizes, int n_in,
                              void* d_out, int out_size, void* d_ws, size_t ws_size,
                              hipStream_t stream) {
  const float* feat = (const float*)d_in[0];
  const float* W1 = (const float*)d_in[1];
  const float* b1 = (const float*)d_in[2];
  const float* W2 = (const float*)d_in[3];
  const float* b2 = (const float*)d_in[4];
  const float* W3 = (const float*)d_in[5];
  const float* b3 = (const float*)d_in[6];
  const int* src = (const int*)d_in[7];
  const int* dst = (const int*)d_in[8];
  const int N = in_sizes[0] / 64;
  const int E = in_sizes[7];
  float* out = (float*)d_out;

  // workspace layout
  float* B            = (float*)d_ws;                     // agg1, N*64 fp32
  unsigned short* zb  = (unsigned short*)(B + (size_t)N * 64);  // z1/z2 bf16 N*64
  unsigned short* z3b = zb + (size_t)N * 64;              // z3, N*16 bf16
  int* cntA  = (int*)(z3b + (size_t)N * 16);              // NHB  } one memset
  float* cs1 = (float*)(cntA + NHB);                      // 64   } covers
  float* cs2 = cs1 + 64;                                  // 64   } these 3
  int* baseA    = (int*)(cs2 + 64);                       // NHB+1
  int* curA     = baseA + NHB + 1;                        // NHB
  int* rowstart = curA + NHB;                             // N+1
  int* csr      = rowstart + N + 1;                       // E
  // ppack aliases zb (dead until matnorm1 writes it, after fillsort)
  unsigned* ppack = (unsigned*)zb;                        // E uints <= N*64*2 B

  const int NHI = (N + 1023) >> 10;     // 98
  const int node_blocks = (N + 3) / 4;  // 4 waves of 64 per block
  const float invN = 1.0f / (float)N;

  // ---- CSR build + layer-1 colsum ----
  hipMemsetAsync(cntA, 0, (NHB + 128) * sizeof(int), stream);  // cntA+cs1+cs2
  prelude_kernel<<<512, 256, 0, stream>>>(dst, cntA, E, feat, cs1, N * 16);
  scanA_kernel<<<1, 64, 0, stream>>>(cntA, baseA, curA, NHI);
  scatterA_kernel<<<512, 256, 0, stream>>>(src, dst, curA, ppack, E);
  fillsort_kernel<<<NHI, 1024, 0, stream>>>(ppack, baseA, rowstart, csr, N, E);

  // ---- layer 1 ----
  matnorm_kernel<<<1024, 256, 0, stream>>>(feat, W1, cs1, zb, N, invN);
  gather64_kernel<<<node_blocks, 256, 0, stream>>>(zb, b1, rowstart, csr, B, N);

  // ---- layer 2 (B pre-relu'd; z2 reuses zb) ----
  colsum_kernel<<<512, 256, 0, stream>>>(B, cs2, N * 16);
  matnorm_kernel<<<1024, 256, 0, stream>>>(B, W2, cs2, zb, N, invN);
  gather_l2_kernel<<<node_blocks, 256, 0, stream>>>(zb, b2, W3, rowstart, csr,
                                                    z3b, N);

  // ---- layer 3 final aggregation ----
  gather16_kernel<<<node_blocks, 256, 0, stream>>>(z3b, b3, rowstart, csr, out, N);
}

// Round 13
// 405.519 us; speedup vs baseline: 1.2925x; 1.0108x over previous
//
#include <hip/hip_runtime.h>

// GCN: N=100000 nodes, E=1600000 edges, F_IN=F_HID=64, F_OUT=16, fp32.
//
// R12 -> R13: gather_l2's fused W3 matvec added ~29 us (vs ~12 standalone):
// VALUBusy 43%, HBM 16% -> serial 64x readlane->fmaf chain (~256 dep cycles)
// with nothing to overlap. Fix (applied to every serial FMA chain): 4
// independent accumulator chains, k interleaved mod 4:
//   - gather_l2 epilogue matvec (4 chains, 4 W3 loads in flight)
//   - matnorm inner matvec + cm staging loop
// No structural changes otherwise (R7/R9/R11: don't bundle gambles).

#define NHB 128     // max hi-buckets of 1024 nodes (N <= 131072); hi = dst >> 10

__device__ __forceinline__ unsigned short f2bf(float f) {
  unsigned u = __builtin_bit_cast(unsigned, f);
  u += 0x7FFFu + ((u >> 16) & 1u);    // round-to-nearest-even
  return (unsigned short)(u >> 16);
}
__device__ __forceinline__ float bf2f(unsigned short h) {
  return __builtin_bit_cast(float, ((unsigned)h) << 16);
}
__device__ __forceinline__ float rlane(float v, int k) {
  return __builtin_bit_cast(
      float, __builtin_amdgcn_readlane(__builtin_bit_cast(int, v), k));
}

// ------- prelude: cntA histogram of dst (hi-buckets) + column sums of feat -------
__global__ __launch_bounds__(256) void prelude_kernel(
    const int* __restrict__ dst, int* __restrict__ cntA, int E,
    const float* __restrict__ x, float* __restrict__ cs, int n4) {
  __shared__ int lc[NHB];
  __shared__ float lds[16][64];
  const int t = threadIdx.x;
  if (t < NHB) lc[t] = 0;
  __syncthreads();
  const int stride = gridDim.x * blockDim.x;
  for (int e = blockIdx.x * blockDim.x + t; e < E; e += stride)
    atomicAdd(&lc[__builtin_nontemporal_load(&dst[e]) >> 10], 1);

  float s0 = 0.f, s1 = 0.f, s2 = 0.f, s3 = 0.f;
  for (int i = blockIdx.x * blockDim.x + t; i < n4; i += stride) {
    float4 v = ((const float4*)x)[i];
    s0 += v.x; s1 += v.y; s2 += v.z; s3 += v.w;
  }
  const int r = t >> 4;
  const int cq = (t & 15) * 4;
  lds[r][cq + 0] = s0; lds[r][cq + 1] = s1; lds[r][cq + 2] = s2; lds[r][cq + 3] = s3;
  __syncthreads();
  if (t < NHB && lc[t]) atomicAdd(&cntA[t], lc[t]);
  if (t < 64) {
    float tot = 0.f;
    #pragma unroll
    for (int rr = 0; rr < 16; ++rr) tot += lds[rr][t];
    unsafeAtomicAdd(&cs[t], tot);
  }
}

// ---------------- column sums of B (already relu'd by gather64) ----------------
__global__ void colsum_kernel(const float* __restrict__ x, float* __restrict__ cs,
                              int n4) {
  __shared__ float lds[16][64];
  float s0 = 0.f, s1 = 0.f, s2 = 0.f, s3 = 0.f;
  const int t = threadIdx.x;
  const int stride = gridDim.x * blockDim.x;
  for (int i = blockIdx.x * blockDim.x + t; i < n4; i += stride) {
    float4 v = ((const float4*)x)[i];
    s0 += v.x; s1 += v.y; s2 += v.z; s3 += v.w;
  }
  const int r = t >> 4;
  const int cq = (t & 15) * 4;
  lds[r][cq + 0] = s0; lds[r][cq + 1] = s1; lds[r][cq + 2] = s2; lds[r][cq + 3] = s3;
  __syncthreads();
  if (t < 64) {
    float tot = 0.f;
    #pragma unroll
    for (int rr = 0; rr < 16; ++rr) tot += lds[rr][t];
    unsafeAtomicAdd(&cs[t], tot);
  }
}

// ------------- fused: z = (x @ W) * rinv - cm, bf16 out; 4-chain FMA -------------
__global__ __launch_bounds__(256) void matnorm_kernel(
    const float* x, const float* __restrict__ W,
    const float* __restrict__ cs, unsigned short* __restrict__ z,
    int N, float invN) {
  const int lane = threadIdx.x & 63;
  const int wid  = blockIdx.x * (blockDim.x >> 6) + (threadIdx.x >> 6);
  const int nw   = gridDim.x * (blockDim.x >> 6);

  float w[64];
  float cm0 = 0.f, cm1 = 0.f, cm2 = 0.f, cm3 = 0.f;
  #pragma unroll
  for (int k = 0; k < 64; k += 4) {
    w[k + 0] = W[(k + 0) * 64 + lane];
    w[k + 1] = W[(k + 1) * 64 + lane];
    w[k + 2] = W[(k + 2) * 64 + lane];
    w[k + 3] = W[(k + 3) * 64 + lane];
    cm0 = fmaf(cs[k + 0], w[k + 0], cm0);
    cm1 = fmaf(cs[k + 1], w[k + 1], cm1);
    cm2 = fmaf(cs[k + 2], w[k + 2], cm2);
    cm3 = fmaf(cs[k + 3], w[k + 3], cm3);
  }
  const float cm = ((cm0 + cm1) + (cm2 + cm3)) * invN;

  for (int row = wid; row < N; row += nw) {
    const float xv = x[(size_t)row * 64 + lane];
    float ss = xv * xv;
    #pragma unroll
    for (int m = 1; m < 64; m <<= 1) ss += __shfl_xor(ss, m, 64);
    const float rinv = 1.0f / sqrtf(1e-6f + ss);
    float a0 = 0.f, a1 = 0.f, a2 = 0.f, a3 = 0.f;
    #pragma unroll
    for (int k = 0; k < 64; k += 4) {
      a0 = fmaf(rlane(xv, k + 0), w[k + 0], a0);
      a1 = fmaf(rlane(xv, k + 1), w[k + 1], a1);
      a2 = fmaf(rlane(xv, k + 2), w[k + 2], a2);
      a3 = fmaf(rlane(xv, k + 3), w[k + 3], a3);
    }
    const float acc = (a0 + a1) + (a2 + a3);
    z[(size_t)row * 64 + lane] = f2bf(acc * rinv - cm);
  }
}

// ================= CSR build: hi-bucket radix + LDS counting sort =================
// Edge packed as (src << 10) | (dst & 1023): src < 2^17 -> 27 bits used.

__global__ void scanA_kernel(const int* __restrict__ cntA,
                             int* __restrict__ baseA, int* __restrict__ curA,
                             int NHI) {
  if (threadIdx.x == 0) {
    int acc = 0;
    for (int p = 0; p < NHI; ++p) { baseA[p] = acc; curA[p] = acc; acc += cntA[p]; }
    baseA[NHI] = acc;
  }
}

#define TILE 2048
#define CAPA 48   // per-tile per-bucket mean 21, sigma 4.6 -> ~6 sigma + spill
__global__ __launch_bounds__(256) void scatterA_kernel(
    const int* __restrict__ src, const int* __restrict__ dst,
    int* __restrict__ curA, unsigned* __restrict__ ppack, int E) {
  __shared__ unsigned lpk[NHB][CAPA];
  __shared__ int lcnt[NHB], lbase[NHB];
  const int t = threadIdx.x;
  if (t < NHB) lcnt[t] = 0;
  __syncthreads();
  const int ntiles = (E + TILE - 1) / TILE;
  for (int tile = blockIdx.x; tile < ntiles; tile += gridDim.x) {
    const int base = tile * TILE;
    #pragma unroll
    for (int j = 0; j < TILE / 256; ++j) {
      const int e = base + j * 256 + t;   // coalesced
      if (e < E) {
        const int d = __builtin_nontemporal_load(&dst[e]);
        const int s = __builtin_nontemporal_load(&src[e]);
        const unsigned pw = ((unsigned)s << 10) | ((unsigned)d & 1023u);
        const int p = d >> 10;
        const int slot = atomicAdd(&lcnt[p], 1);
        if (slot < CAPA) lpk[p][slot] = pw;
        else ppack[atomicAdd(&curA[p], 1)] = pw;  // rare spill
      }
    }
    __syncthreads();
    if (t < NHB) {
      int c = lcnt[t]; if (c > CAPA) c = CAPA;
      lbase[t] = c ? atomicAdd(&curA[t], c) : 0;
      lcnt[t] = c;
    }
    __syncthreads();
    for (int p = 0; p < NHB; ++p) {
      const int c = lcnt[p];
      if (t < c) ppack[lbase[p] + t] = lpk[p][t];  // contiguous chunk
    }
    __syncthreads();
    if (t < NHB) lcnt[t] = 0;
    __syncthreads();
  }
}

// One workgroup (1024 thr) per 1024-node bucket: LDS counting sort by exact dst.
__global__ __launch_bounds__(1024) void fillsort_kernel(
    const unsigned* __restrict__ ppack, const int* __restrict__ baseA,
    int* __restrict__ rowstart, int* __restrict__ csr, int N, int E) {
  __shared__ int hist[1024];
  __shared__ int bs[1024];
  const int t = threadIdx.x;
  const int h = blockIdx.x;
  const int nlo = h << 10;
  const int elo = baseA[h], ehi = baseA[h + 1];

  hist[t] = 0;
  __syncthreads();

  // phase 1: histogram (4 independent loads in flight)
  int e = elo + t;
  for (; e + 3 * 1024 < ehi; e += 4 * 1024) {
    const unsigned p0 = ppack[e], p1 = ppack[e + 1024],
                   p2 = ppack[e + 2048], p3 = ppack[e + 3072];
    atomicAdd(&hist[p0 & 1023u], 1); atomicAdd(&hist[p1 & 1023u], 1);
    atomicAdd(&hist[p2 & 1023u], 1); atomicAdd(&hist[p3 & 1023u], 1);
  }
  for (; e < ehi; e += 1024) atomicAdd(&hist[ppack[e] & 1023u], 1);
  __syncthreads();

  // exclusive scan (1024-wide Hillis-Steele, 1 counter/thread)
  const int c = hist[t];
  bs[t] = c;
  __syncthreads();
  for (int off = 1; off < 1024; off <<= 1) {
    const int v = (t >= off) ? bs[t - off] : 0;
    __syncthreads();
    bs[t] += v;
    __syncthreads();
  }
  const int excl = bs[t] - c;

  hist[t] = excl;                    // LDS cursor
  const int n0 = nlo + t;
  if (n0 < N) rowstart[n0] = elo + excl;
  if (h == 0 && t == 0) rowstart[N] = E;
  __syncthreads();

  // phase 2: place (bucket's csr window ~65 KB, single CU owner)
  e = elo + t;
  for (; e + 3 * 1024 < ehi; e += 4 * 1024) {
    const unsigned p0 = ppack[e],        p1 = ppack[e + 1024];
    const unsigned p2 = ppack[e + 2048], p3 = ppack[e + 3072];
    csr[elo + atomicAdd(&hist[p0 & 1023u], 1)] = (int)(p0 >> 10);
    csr[elo + atomicAdd(&hist[p1 & 1023u], 1)] = (int)(p1 >> 10);
    csr[elo + atomicAdd(&hist[p2 & 1023u], 1)] = (int)(p2 >> 10);
    csr[elo + atomicAdd(&hist[p3 & 1023u], 1)] = (int)(p3 >> 10);
  }
  for (; e < ehi; e += 1024) {
    const unsigned p = ppack[e];
    csr[elo + atomicAdd(&hist[p & 1023u], 1)] = (int)(p >> 10);
  }
}

// ------- gather64: agg[d] = relu(z[d] + b + sum_{e} z[src_e]) -------
// R8's proven form: one node/wave then exit; 16-deep ILP; uniform scalar base.
__global__ __launch_bounds__(256) void gather64_kernel(
    const unsigned short* __restrict__ z, const float* __restrict__ b,
    const int* __restrict__ rowstart, const int* __restrict__ csr,
    float* __restrict__ agg, int N) {
  const int lane = threadIdx.x & 63;
  int node = blockIdx.x * (blockDim.x >> 6) + (threadIdx.x >> 6);
  if (node >= N) return;
  node = __builtin_amdgcn_readfirstlane(node);
  const int start = rowstart[node];
  const int end   = rowstart[node + 1];
  const unsigned short hs = z[(size_t)node * 64 + lane];
  float a0 = 0.f, a1 = 0.f, a2 = 0.f, a3 = 0.f;
  int e = start;
  for (; e + 16 <= end; e += 16) {
    unsigned short h[16];
    #pragma unroll
    for (int j = 0; j < 16; ++j) h[j] = z[(size_t)csr[e + j] * 64 + lane];
    #pragma unroll
    for (int j = 0; j < 16; j += 4) {
      a0 += bf2f(h[j + 0]); a1 += bf2f(h[j + 1]);
      a2 += bf2f(h[j + 2]); a3 += bf2f(h[j + 3]);
    }
  }
  for (; e + 4 <= end; e += 4) {
    unsigned short h[4];
    #pragma unroll
    for (int j = 0; j < 4; ++j) h[j] = z[(size_t)csr[e + j] * 64 + lane];
    a0 += bf2f(h[0]); a1 += bf2f(h[1]); a2 += bf2f(h[2]); a3 += bf2f(h[3]);
  }
  for (; e < end; ++e) a0 += bf2f(z[(size_t)csr[e] * 64 + lane]);
  const float sum = (a0 + a1) + (a2 + a3);
  agg[(size_t)node * 64 + lane] = fmaxf(bf2f(hs) + b[lane] + sum, 0.f);
}

// ------- gather_l2: o = relu(z2[d] + b2 + sum z2[src]); z3 = o @ W3 (bf16) -------
// Barrier-free fused 64->16 matvec epilogue, 4 independent FMA chains.
__global__ __launch_bounds__(256) void gather_l2_kernel(
    const unsigned short* __restrict__ z2, const float* __restrict__ b2,
    const float* __restrict__ W3, const int* __restrict__ rowstart,
    const int* __restrict__ csr, unsigned short* __restrict__ z3, int N) {
  const int lane = threadIdx.x & 63;
  int node = blockIdx.x * (blockDim.x >> 6) + (threadIdx.x >> 6);
  if (node >= N) return;
  node = __builtin_amdgcn_readfirstlane(node);
  const int start = rowstart[node];
  const int end   = rowstart[node + 1];
  const unsigned short hs = z2[(size_t)node * 64 + lane];
  float a0 = 0.f, a1 = 0.f, a2 = 0.f, a3 = 0.f;
  int e = start;
  for (; e + 16 <= end; e += 16) {
    unsigned short h[16];
    #pragma unroll
    for (int j = 0; j < 16; ++j) h[j] = z2[(size_t)csr[e + j] * 64 + lane];
    #pragma unroll
    for (int j = 0; j < 16; j += 4) {
      a0 += bf2f(h[j + 0]); a1 += bf2f(h[j + 1]);
      a2 += bf2f(h[j + 2]); a3 += bf2f(h[j + 3]);
    }
  }
  for (; e + 4 <= end; e += 4) {
    unsigned short h[4];
    #pragma unroll
    for (int j = 0; j < 4; ++j) h[j] = z2[(size_t)csr[e + j] * 64 + lane];
    a0 += bf2f(h[0]); a1 += bf2f(h[1]); a2 += bf2f(h[2]); a3 += bf2f(h[3]);
  }
  for (; e < end; ++e) a0 += bf2f(z2[(size_t)csr[e] * 64 + lane]);
  const float sum = (a0 + a1) + (a2 + a3);
  const float o = fmaxf(bf2f(hs) + b2[lane] + sum, 0.f);
  // fused 64->16 matvec, 4 chains: z3[j] = sum_k o[k] * W3[k][j]
  const int j = lane & 15;
  float m0 = 0.f, m1 = 0.f, m2 = 0.f, m3 = 0.f;
  #pragma unroll
  for (int k = 0; k < 64; k += 4) {
    m0 = fmaf(rlane(o, k + 0), W3[(k + 0) * 16 + j], m0);
    m1 = fmaf(rlane(o, k + 1), W3[(k + 1) * 16 + j], m1);
    m2 = fmaf(rlane(o, k + 2), W3[(k + 2) * 16 + j], m2);
    m3 = fmaf(rlane(o, k + 3), W3[(k + 3) * 16 + j], m3);
  }
  if (lane < 16) z3[(size_t)node * 16 + lane] = f2bf((m0 + m1) + (m2 + m3));
}

// ------- gather16: out[d] = z3[d] + b3 + sum z3[src]; 16 feat x 4 edge-groups -------
__global__ __launch_bounds__(256) void gather16_kernel(
    const unsigned short* __restrict__ z3, const float* __restrict__ b3,
    const int* __restrict__ rowstart, const int* __restrict__ csr,
    float* __restrict__ out, int N) {
  const int lane = threadIdx.x & 63;
  const int f = lane & 15;
  const int g = lane >> 4;
  int node = blockIdx.x * (blockDim.x >> 6) + (threadIdx.x >> 6);
  if (node >= N) return;
  node = __builtin_amdgcn_readfirstlane(node);
  const int start = rowstart[node];
  const int end   = rowstart[node + 1];
  float acc0 = 0.f, acc1 = 0.f;
  int e = start + g;
  for (; e + 4 < end; e += 8) {
    acc0 += bf2f(z3[(size_t)csr[e] * 16 + f]);
    acc1 += bf2f(z3[(size_t)csr[e + 4] * 16 + f]);
  }
  if (e < end) acc0 += bf2f(z3[(size_t)csr[e] * 16 + f]);
  float acc = acc0 + acc1;
  acc += __shfl_xor(acc, 16, 64);
  acc += __shfl_xor(acc, 32, 64);
  if (lane < 16)
    out[(size_t)node * 16 + f] = bf2f(z3[(size_t)node * 16 + f]) + b3[f] + acc;
}

extern "C" void kernel_launch(void* const* d_in, const int* in_sizes, int n_in,
                              void* d_out, int out_size, void* d_ws, size_t ws_size,
                              hipStream_t stream) {
  const float* feat = (const float*)d_in[0];
  const float* W1 = (const float*)d_in[1];
  const float* b1 = (const float*)d_in[2];
  const float* W2 = (const float*)d_in[3];
  const float* b2 = (const float*)d_in[4];
  const float* W3 = (const float*)d_in[5];
  const float* b3 = (const float*)d_in[6];
  const int* src = (const int*)d_in[7];
  const int* dst = (const int*)d_in[8];
  const int N = in_sizes[0] / 64;
  const int E = in_sizes[7];
  float* out = (float*)d_out;

  // workspace layout
  float* B            = (float*)d_ws;                     // agg1, N*64 fp32
  unsigned short* zb  = (unsigned short*)(B + (size_t)N * 64);  // z1/z2 bf16 N*64
  unsigned short* z3b = zb + (size_t)N * 64;              // z3, N*16 bf16
  int* cntA  = (int*)(z3b + (size_t)N * 16);              // NHB  } one memset
  float* cs1 = (float*)(cntA + NHB);                      // 64   } covers
  float* cs2 = cs1 + 64;                                  // 64   } these 3
  int* baseA    = (int*)(cs2 + 64);                       // NHB+1
  int* curA     = baseA + NHB + 1;                        // NHB
  int* rowstart = curA + NHB;                             // N+1
  int* csr      = rowstart + N + 1;                       // E
  // ppack aliases zb (dead until matnorm1 writes it, after fillsort)
  unsigned* ppack = (unsigned*)zb;                        // E uints <= N*64*2 B

  const int NHI = (N + 1023) >> 10;     // 98
  const int node_blocks = (N + 3) / 4;  // 4 waves of 64 per block
  const float invN = 1.0f / (float)N;

  // ---- CSR build + layer-1 colsum ----
  hipMemsetAsync(cntA, 0, (NHB + 128) * sizeof(int), stream);  // cntA+cs1+cs2
  prelude_kernel<<<512, 256, 0, stream>>>(dst, cntA, E, feat, cs1, N * 16);
  scanA_kernel<<<1, 64, 0, stream>>>(cntA, baseA, curA, NHI);
  scatterA_kernel<<<512, 256, 0, stream>>>(src, dst, curA, ppack, E);
  fillsort_kernel<<<NHI, 1024, 0, stream>>>(ppack, baseA, rowstart, csr, N, E);

  // ---- layer 1 ----
  matnorm_kernel<<<1024, 256, 0, stream>>>(feat, W1, cs1, zb, N, invN);
  gather64_kernel<<<node_blocks, 256, 0, stream>>>(zb, b1, rowstart, csr, B, N);

  // ---- layer 2 (B pre-relu'd; z2 reuses zb) ----
  colsum_kernel<<<512, 256, 0, stream>>>(B, cs2, N * 16);
  matnorm_kernel<<<1024, 256, 0, stream>>>(B, W2, cs2, zb, N, invN);
  gather_l2_kernel<<<node_blocks, 256, 0, stream>>>(zb, b2, W3, rowstart, csr,
                                                    z3b, N);

  // ---- layer 3 final aggregation ----
  gather16_kernel<<<node_blocks, 256, 0, stream>>>(z3b, b3, rowstart, csr, out, N);
}

// Round 14
// 400.087 us; speedup vs baseline: 1.3100x; 1.0136x over previous
//
#include <hip/hip_runtime.h>

// GCN: N=100000 nodes, E=1600000 edges, F_IN=F_HID=64, F_OUT=16, fp32.
//
// R13 -> R14: gather_l2's epilogue was VMEM-ISSUE bound, not FMA-latency
// bound (64 scattered W3 loads/node -> wave VMEM count 21 -> 85; ~4cy/issue
// explains the 43 -> 72 us delta). Fix: transposed matvec. Each lane owns W3
// ROW lane (4 float4 loads, issued before the gather), computes 16 partials
// o*W3[lane][m], then a split-butterfly reduction (xor 1/2/4/8 halving accs,
// then xor 16/32). Per node: 64 VMEM + 128 VALU -> 4 VMEM + ~100 VALU.
// Lane l<16 ends with output column bitrev4(l). Gather core untouched.

#define NHB 128     // max hi-buckets of 1024 nodes (N <= 131072); hi = dst >> 10

__device__ __forceinline__ unsigned short f2bf(float f) {
  unsigned u = __builtin_bit_cast(unsigned, f);
  u += 0x7FFFu + ((u >> 16) & 1u);    // round-to-nearest-even
  return (unsigned short)(u >> 16);
}
__device__ __forceinline__ float bf2f(unsigned short h) {
  return __builtin_bit_cast(float, ((unsigned)h) << 16);
}
__device__ __forceinline__ float rlane(float v, int k) {
  return __builtin_bit_cast(
      float, __builtin_amdgcn_readlane(__builtin_bit_cast(int, v), k));
}

// ------- prelude: cntA histogram of dst (hi-buckets) + column sums of feat -------
__global__ __launch_bounds__(256) void prelude_kernel(
    const int* __restrict__ dst, int* __restrict__ cntA, int E,
    const float* __restrict__ x, float* __restrict__ cs, int n4) {
  __shared__ int lc[NHB];
  __shared__ float lds[16][64];
  const int t = threadIdx.x;
  if (t < NHB) lc[t] = 0;
  __syncthreads();
  const int stride = gridDim.x * blockDim.x;
  for (int e = blockIdx.x * blockDim.x + t; e < E; e += stride)
    atomicAdd(&lc[__builtin_nontemporal_load(&dst[e]) >> 10], 1);

  float s0 = 0.f, s1 = 0.f, s2 = 0.f, s3 = 0.f;
  for (int i = blockIdx.x * blockDim.x + t; i < n4; i += stride) {
    float4 v = ((const float4*)x)[i];
    s0 += v.x; s1 += v.y; s2 += v.z; s3 += v.w;
  }
  const int r = t >> 4;
  const int cq = (t & 15) * 4;
  lds[r][cq + 0] = s0; lds[r][cq + 1] = s1; lds[r][cq + 2] = s2; lds[r][cq + 3] = s3;
  __syncthreads();
  if (t < NHB && lc[t]) atomicAdd(&cntA[t], lc[t]);
  if (t < 64) {
    float tot = 0.f;
    #pragma unroll
    for (int rr = 0; rr < 16; ++rr) tot += lds[rr][t];
    unsafeAtomicAdd(&cs[t], tot);
  }
}

// ---------------- column sums of B (already relu'd by gather64) ----------------
__global__ void colsum_kernel(const float* __restrict__ x, float* __restrict__ cs,
                              int n4) {
  __shared__ float lds[16][64];
  float s0 = 0.f, s1 = 0.f, s2 = 0.f, s3 = 0.f;
  const int t = threadIdx.x;
  const int stride = gridDim.x * blockDim.x;
  for (int i = blockIdx.x * blockDim.x + t; i < n4; i += stride) {
    float4 v = ((const float4*)x)[i];
    s0 += v.x; s1 += v.y; s2 += v.z; s3 += v.w;
  }
  const int r = t >> 4;
  const int cq = (t & 15) * 4;
  lds[r][cq + 0] = s0; lds[r][cq + 1] = s1; lds[r][cq + 2] = s2; lds[r][cq + 3] = s3;
  __syncthreads();
  if (t < 64) {
    float tot = 0.f;
    #pragma unroll
    for (int rr = 0; rr < 16; ++rr) tot += lds[rr][t];
    unsafeAtomicAdd(&cs[t], tot);
  }
}

// ------------- fused: z = (x @ W) * rinv - cm, bf16 out; 4-chain FMA -------------
__global__ __launch_bounds__(256) void matnorm_kernel(
    const float* x, const float* __restrict__ W,
    const float* __restrict__ cs, unsigned short* __restrict__ z,
    int N, float invN) {
  const int lane = threadIdx.x & 63;
  const int wid  = blockIdx.x * (blockDim.x >> 6) + (threadIdx.x >> 6);
  const int nw   = gridDim.x * (blockDim.x >> 6);

  float w[64];
  float cm0 = 0.f, cm1 = 0.f, cm2 = 0.f, cm3 = 0.f;
  #pragma unroll
  for (int k = 0; k < 64; k += 4) {
    w[k + 0] = W[(k + 0) * 64 + lane];
    w[k + 1] = W[(k + 1) * 64 + lane];
    w[k + 2] = W[(k + 2) * 64 + lane];
    w[k + 3] = W[(k + 3) * 64 + lane];
    cm0 = fmaf(cs[k + 0], w[k + 0], cm0);
    cm1 = fmaf(cs[k + 1], w[k + 1], cm1);
    cm2 = fmaf(cs[k + 2], w[k + 2], cm2);
    cm3 = fmaf(cs[k + 3], w[k + 3], cm3);
  }
  const float cm = ((cm0 + cm1) + (cm2 + cm3)) * invN;

  for (int row = wid; row < N; row += nw) {
    const float xv = x[(size_t)row * 64 + lane];
    float ss = xv * xv;
    #pragma unroll
    for (int m = 1; m < 64; m <<= 1) ss += __shfl_xor(ss, m, 64);
    const float rinv = 1.0f / sqrtf(1e-6f + ss);
    float a0 = 0.f, a1 = 0.f, a2 = 0.f, a3 = 0.f;
    #pragma unroll
    for (int k = 0; k < 64; k += 4) {
      a0 = fmaf(rlane(xv, k + 0), w[k + 0], a0);
      a1 = fmaf(rlane(xv, k + 1), w[k + 1], a1);
      a2 = fmaf(rlane(xv, k + 2), w[k + 2], a2);
      a3 = fmaf(rlane(xv, k + 3), w[k + 3], a3);
    }
    const float acc = (a0 + a1) + (a2 + a3);
    z[(size_t)row * 64 + lane] = f2bf(acc * rinv - cm);
  }
}

// ================= CSR build: hi-bucket radix + LDS counting sort =================
// Edge packed as (src << 10) | (dst & 1023): src < 2^17 -> 27 bits used.

__global__ void scanA_kernel(const int* __restrict__ cntA,
                             int* __restrict__ baseA, int* __restrict__ curA,
                             int NHI) {
  if (threadIdx.x == 0) {
    int acc = 0;
    for (int p = 0; p < NHI; ++p) { baseA[p] = acc; curA[p] = acc; acc += cntA[p]; }
    baseA[NHI] = acc;
  }
}

#define TILE 2048
#define CAPA 48   // per-tile per-bucket mean 21, sigma 4.6 -> ~6 sigma + spill
__global__ __launch_bounds__(256) void scatterA_kernel(
    const int* __restrict__ src, const int* __restrict__ dst,
    int* __restrict__ curA, unsigned* __restrict__ ppack, int E) {
  __shared__ unsigned lpk[NHB][CAPA];
  __shared__ int lcnt[NHB], lbase[NHB];
  const int t = threadIdx.x;
  if (t < NHB) lcnt[t] = 0;
  __syncthreads();
  const int ntiles = (E + TILE - 1) / TILE;
  for (int tile = blockIdx.x; tile < ntiles; tile += gridDim.x) {
    const int base = tile * TILE;
    #pragma unroll
    for (int j = 0; j < TILE / 256; ++j) {
      const int e = base + j * 256 + t;   // coalesced
      if (e < E) {
        const int d = __builtin_nontemporal_load(&dst[e]);
        const int s = __builtin_nontemporal_load(&src[e]);
        const unsigned pw = ((unsigned)s << 10) | ((unsigned)d & 1023u);
        const int p = d >> 10;
        const int slot = atomicAdd(&lcnt[p], 1);
        if (slot < CAPA) lpk[p][slot] = pw;
        else ppack[atomicAdd(&curA[p], 1)] = pw;  // rare spill
      }
    }
    __syncthreads();
    if (t < NHB) {
      int c = lcnt[t]; if (c > CAPA) c = CAPA;
      lbase[t] = c ? atomicAdd(&curA[t], c) : 0;
      lcnt[t] = c;
    }
    __syncthreads();
    for (int p = 0; p < NHB; ++p) {
      const int c = lcnt[p];
      if (t < c) ppack[lbase[p] + t] = lpk[p][t];  // contiguous chunk
    }
    __syncthreads();
    if (t < NHB) lcnt[t] = 0;
    __syncthreads();
  }
}

// One workgroup (1024 thr) per 1024-node bucket: LDS counting sort by exact dst.
__global__ __launch_bounds__(1024) void fillsort_kernel(
    const unsigned* __restrict__ ppack, const int* __restrict__ baseA,
    int* __restrict__ rowstart, int* __restrict__ csr, int N, int E) {
  __shared__ int hist[1024];
  __shared__ int bs[1024];
  const int t = threadIdx.x;
  const int h = blockIdx.x;
  const int nlo = h << 10;
  const int elo = baseA[h], ehi = baseA[h + 1];

  hist[t] = 0;
  __syncthreads();

  // phase 1: histogram (4 independent loads in flight)
  int e = elo + t;
  for (; e + 3 * 1024 < ehi; e += 4 * 1024) {
    const unsigned p0 = ppack[e], p1 = ppack[e + 1024],
                   p2 = ppack[e + 2048], p3 = ppack[e + 3072];
    atomicAdd(&hist[p0 & 1023u], 1); atomicAdd(&hist[p1 & 1023u], 1);
    atomicAdd(&hist[p2 & 1023u], 1); atomicAdd(&hist[p3 & 1023u], 1);
  }
  for (; e < ehi; e += 1024) atomicAdd(&hist[ppack[e] & 1023u], 1);
  __syncthreads();

  // exclusive scan (1024-wide Hillis-Steele, 1 counter/thread)
  const int c = hist[t];
  bs[t] = c;
  __syncthreads();
  for (int off = 1; off < 1024; off <<= 1) {
    const int v = (t >= off) ? bs[t - off] : 0;
    __syncthreads();
    bs[t] += v;
    __syncthreads();
  }
  const int excl = bs[t] - c;

  hist[t] = excl;                    // LDS cursor
  const int n0 = nlo + t;
  if (n0 < N) rowstart[n0] = elo + excl;
  if (h == 0 && t == 0) rowstart[N] = E;
  __syncthreads();

  // phase 2: place (bucket's csr window ~65 KB, single CU owner)
  e = elo + t;
  for (; e + 3 * 1024 < ehi; e += 4 * 1024) {
    const unsigned p0 = ppack[e],        p1 = ppack[e + 1024];
    const unsigned p2 = ppack[e + 2048], p3 = ppack[e + 3072];
    csr[elo + atomicAdd(&hist[p0 & 1023u], 1)] = (int)(p0 >> 10);
    csr[elo + atomicAdd(&hist[p1 & 1023u], 1)] = (int)(p1 >> 10);
    csr[elo + atomicAdd(&hist[p2 & 1023u], 1)] = (int)(p2 >> 10);
    csr[elo + atomicAdd(&hist[p3 & 1023u], 1)] = (int)(p3 >> 10);
  }
  for (; e < ehi; e += 1024) {
    const unsigned p = ppack[e];
    csr[elo + atomicAdd(&hist[p & 1023u], 1)] = (int)(p >> 10);
  }
}

// ------- gather64: agg[d] = relu(z[d] + b + sum_{e} z[src_e]) -------
// R8's proven form: one node/wave then exit; 16-deep ILP; uniform scalar base.
__global__ __launch_bounds__(256) void gather64_kernel(
    const unsigned short* __restrict__ z, const float* __restrict__ b,
    const int* __restrict__ rowstart, const int* __restrict__ csr,
    float* __restrict__ agg, int N) {
  const int lane = threadIdx.x & 63;
  int node = blockIdx.x * (blockDim.x >> 6) + (threadIdx.x >> 6);
  if (node >= N) return;
  node = __builtin_amdgcn_readfirstlane(node);
  const int start = rowstart[node];
  const int end   = rowstart[node + 1];
  const unsigned short hs = z[(size_t)node * 64 + lane];
  float a0 = 0.f, a1 = 0.f, a2 = 0.f, a3 = 0.f;
  int e = start;
  for (; e + 16 <= end; e += 16) {
    unsigned short h[16];
    #pragma unroll
    for (int j = 0; j < 16; ++j) h[j] = z[(size_t)csr[e + j] * 64 + lane];
    #pragma unroll
    for (int j = 0; j < 16; j += 4) {
      a0 += bf2f(h[j + 0]); a1 += bf2f(h[j + 1]);
      a2 += bf2f(h[j + 2]); a3 += bf2f(h[j + 3]);
    }
  }
  for (; e + 4 <= end; e += 4) {
    unsigned short h[4];
    #pragma unroll
    for (int j = 0; j < 4; ++j) h[j] = z[(size_t)csr[e + j] * 64 + lane];
    a0 += bf2f(h[0]); a1 += bf2f(h[1]); a2 += bf2f(h[2]); a3 += bf2f(h[3]);
  }
  for (; e < end; ++e) a0 += bf2f(z[(size_t)csr[e] * 64 + lane]);
  const float sum = (a0 + a1) + (a2 + a3);
  agg[(size_t)node * 64 + lane] = fmaxf(bf2f(hs) + b[lane] + sum, 0.f);
}

// ------- gather_l2: o = relu(z2[d] + b2 + sum z2[src]); z3 = o @ W3 (bf16) -------
// Transposed matvec epilogue: lane owns W3 row `lane` (4 float4 loads, issued
// before the gather); 16 partials o*W3[lane][m]; split-butterfly reduction
// (xor 1/2/4/8 halving accs, then xor 16/32). Lane l<16 holds col bitrev4(l).
__global__ __launch_bounds__(256) void gather_l2_kernel(
    const unsigned short* __restrict__ z2, const float* __restrict__ b2,
    const float* __restrict__ W3, const int* __restrict__ rowstart,
    const int* __restrict__ csr, unsigned short* __restrict__ z3, int N) {
  const int lane = threadIdx.x & 63;
  int node = blockIdx.x * (blockDim.x >> 6) + (threadIdx.x >> 6);
  if (node >= N) return;
  node = __builtin_amdgcn_readfirstlane(node);
  // stage W3 row `lane` early (independent of the gather; 4 VMEM total)
  float4 w4[4];
  #pragma unroll
  for (int q = 0; q < 4; ++q)
    w4[q] = ((const float4*)(W3 + lane * 16))[q];

  const int start = rowstart[node];
  const int end   = rowstart[node + 1];
  const unsigned short hs = z2[(size_t)node * 64 + lane];
  float a0 = 0.f, a1 = 0.f, a2 = 0.f, a3 = 0.f;
  int e = start;
  for (; e + 16 <= end; e += 16) {
    unsigned short h[16];
    #pragma unroll
    for (int j = 0; j < 16; ++j) h[j] = z2[(size_t)csr[e + j] * 64 + lane];
    #pragma unroll
    for (int j = 0; j < 16; j += 4) {
      a0 += bf2f(h[j + 0]); a1 += bf2f(h[j + 1]);
      a2 += bf2f(h[j + 2]); a3 += bf2f(h[j + 3]);
    }
  }
  for (; e + 4 <= end; e += 4) {
    unsigned short h[4];
    #pragma unroll
    for (int j = 0; j < 4; ++j) h[j] = z2[(size_t)csr[e + j] * 64 + lane];
    a0 += bf2f(h[0]); a1 += bf2f(h[1]); a2 += bf2f(h[2]); a3 += bf2f(h[3]);
  }
  for (; e < end; ++e) a0 += bf2f(z2[(size_t)csr[e] * 64 + lane]);
  const float sum = (a0 + a1) + (a2 + a3);
  const float o = fmaxf(bf2f(hs) + b2[lane] + sum, 0.f);

  // 16 partials: p[m] = o * W3[lane][m]
  float p[16];
  #pragma unroll
  for (int q = 0; q < 4; ++q) {
    p[4 * q + 0] = o * w4[q].x;
    p[4 * q + 1] = o * w4[q].y;
    p[4 * q + 2] = o * w4[q].z;
    p[4 * q + 3] = o * w4[q].w;
  }
  // split-butterfly: xor 1 (16->8), xor 2 (8->4), xor 4 (4->2), xor 8 (2->1)
  {
    const bool up = (lane & 1);
    #pragma unroll
    for (int m = 0; m < 8; ++m) {
      const float mine = up ? p[m + 8] : p[m];
      const float give = up ? p[m] : p[m + 8];
      p[m] = mine + __shfl_xor(give, 1, 64);
    }
  }
  {
    const bool up = (lane & 2);
    #pragma unroll
    for (int m = 0; m < 4; ++m) {
      const float mine = up ? p[m + 4] : p[m];
      const float give = up ? p[m] : p[m + 4];
      p[m] = mine + __shfl_xor(give, 2, 64);
    }
  }
  {
    const bool up = (lane & 4);
    #pragma unroll
    for (int m = 0; m < 2; ++m) {
      const float mine = up ? p[m + 2] : p[m];
      const float give = up ? p[m] : p[m + 2];
      p[m] = mine + __shfl_xor(give, 4, 64);
    }
  }
  {
    const bool up = (lane & 8);
    const float mine = up ? p[1] : p[0];
    const float give = up ? p[0] : p[1];
    p[0] = mine + __shfl_xor(give, 8, 64);
  }
  // pure reductions across remaining lane bits
  p[0] += __shfl_xor(p[0], 16, 64);
  p[0] += __shfl_xor(p[0], 32, 64);

  if (lane < 16) {
    // lane l holds output column bitrev4(l)
    const int j = ((lane & 1) << 3) | ((lane & 2) << 1) |
                  ((lane & 4) >> 1) | ((lane & 8) >> 3);
    z3[(size_t)node * 16 + j] = f2bf(p[0]);
  }
}

// ------- gather16: out[d] = z3[d] + b3 + sum z3[src]; 16 feat x 4 edge-groups -------
__global__ __launch_bounds__(256) void gather16_kernel(
    const unsigned short* __restrict__ z3, const float* __restrict__ b3,
    const int* __restrict__ rowstart, const int* __restrict__ csr,
    float* __restrict__ out, int N) {
  const int lane = threadIdx.x & 63;
  const int f = lane & 15;
  const int g = lane >> 4;
  int node = blockIdx.x * (blockDim.x >> 6) + (threadIdx.x >> 6);
  if (node >= N) return;
  node = __builtin_amdgcn_readfirstlane(node);
  const int start = rowstart[node];
  const int end   = rowstart[node + 1];
  float acc0 = 0.f, acc1 = 0.f;
  int e = start + g;
  for (; e + 4 < end; e += 8) {
    acc0 += bf2f(z3[(size_t)csr[e] * 16 + f]);
    acc1 += bf2f(z3[(size_t)csr[e + 4] * 16 + f]);
  }
  if (e < end) acc0 += bf2f(z3[(size_t)csr[e] * 16 + f]);
  float acc = acc0 + acc1;
  acc += __shfl_xor(acc, 16, 64);
  acc += __shfl_xor(acc, 32, 64);
  if (lane < 16)
    out[(size_t)node * 16 + f] = bf2f(z3[(size_t)node * 16 + f]) + b3[f] + acc;
}

extern "C" void kernel_launch(void* const* d_in, const int* in_sizes, int n_in,
                              void* d_out, int out_size, void* d_ws, size_t ws_size,
                              hipStream_t stream) {
  const float* feat = (const float*)d_in[0];
  const float* W1 = (const float*)d_in[1];
  const float* b1 = (const float*)d_in[2];
  const float* W2 = (const float*)d_in[3];
  const float* b2 = (const float*)d_in[4];
  const float* W3 = (const float*)d_in[5];
  const float* b3 = (const float*)d_in[6];
  const int* src = (const int*)d_in[7];
  const int* dst = (const int*)d_in[8];
  const int N = in_sizes[0] / 64;
  const int E = in_sizes[7];
  float* out = (float*)d_out;

  // workspace layout
  float* B            = (float*)d_ws;                     // agg1, N*64 fp32
  unsigned short* zb  = (unsigned short*)(B + (size_t)N * 64);  // z1/z2 bf16 N*64
  unsigned short* z3b = zb + (size_t)N * 64;              // z3, N*16 bf16
  int* cntA  = (int*)(z3b + (size_t)N * 16);              // NHB  } one memset
  float* cs1 = (float*)(cntA + NHB);                      // 64   } covers
  float* cs2 = cs1 + 64;                                  // 64   } these 3
  int* baseA    = (int*)(cs2 + 64);                       // NHB+1
  int* curA     = baseA + NHB + 1;                        // NHB
  int* rowstart = curA + NHB;                             // N+1
  int* csr      = rowstart + N + 1;                       // E
  // ppack aliases zb (dead until matnorm1 writes it, after fillsort)
  unsigned* ppack = (unsigned*)zb;                        // E uints <= N*64*2 B

  const int NHI = (N + 1023) >> 10;     // 98
  const int node_blocks = (N + 3) / 4;  // 4 waves of 64 per block
  const float invN = 1.0f / (float)N;

  // ---- CSR build + layer-1 colsum ----
  hipMemsetAsync(cntA, 0, (NHB + 128) * sizeof(int), stream);  // cntA+cs1+cs2
  prelude_kernel<<<512, 256, 0, stream>>>(dst, cntA, E, feat, cs1, N * 16);
  scanA_kernel<<<1, 64, 0, stream>>>(cntA, baseA, curA, NHI);
  scatterA_kernel<<<512, 256, 0, stream>>>(src, dst, curA, ppack, E);
  fillsort_kernel<<<NHI, 1024, 0, stream>>>(ppack, baseA, rowstart, csr, N, E);

  // ---- layer 1 ----
  matnorm_kernel<<<1024, 256, 0, stream>>>(feat, W1, cs1, zb, N, invN);
  gather64_kernel<<<node_blocks, 256, 0, stream>>>(zb, b1, rowstart, csr, B, N);

  // ---- layer 2 (B pre-relu'd; z2 reuses zb) ----
  colsum_kernel<<<512, 256, 0, stream>>>(B, cs2, N * 16);
  matnorm_kernel<<<1024, 256, 0, stream>>>(B, W2, cs2, zb, N, invN);
  gather_l2_kernel<<<node_blocks, 256, 0, stream>>>(zb, b2, W3, rowstart, csr,
                                                    z3b, N);

  // ---- layer 3 final aggregation ----
  gather16_kernel<<<node_blocks, 256, 0, stream>>>(z3b, b3, rowstart, csr, out, N);
}